// Round 10
// baseline (293.922 us; speedup 1.0000x reference)
//
#include <hip/hip_runtime.h>
#include <hip/hip_bf16.h>
#include <math.h>

#define D_MODEL 1024
#define SEQ     1024
#define BATCH   4
#define NHEADS  16
#define HD      64

// log2(e) folds: p = exp2(s') with s' = (q.k)*0.125*log2e + 0.05*log2e*vimp
// (kimp term is constant per q-row -> cancels in softmax; dropped entirely)
#define QSC 0.18033688f   // 0.125 * log2(e)
#define BSC 0.072134752f  // 0.05  * log2(e)

typedef __bf16 bf16x8 __attribute__((ext_vector_type(8)));
typedef __bf16 bf16x4 __attribute__((ext_vector_type(4)));
typedef float  f32x4  __attribute__((ext_vector_type(4)));

__device__ __forceinline__ f32x4 mfma16(bf16x8 a, bf16x8 b, f32x4 c) {
  return __builtin_amdgcn_mfma_f32_16x16x32_bf16(a, b, c, 0, 0, 0);
}

// async global->LDS, 16B per lane; LDS dest = wave-uniform base + lane*16
__device__ __forceinline__ void async16(__bf16* lds, const __bf16* g) {
  __builtin_amdgcn_global_load_lds(g, lds, 16, 0, 0);
}

// raw v_exp_f32: args here are bounded (|x| < ~60); flush-to-zero below -126 is
// exactly right for softmax. Skips libm's range-fixup VALU around each call.
__device__ __forceinline__ float fexp2(float x) {
  float r;
  asm volatile("v_exp_f32 %0, %1" : "=v"(r) : "v"(x));
  return r;
}

// ------------------------------------------ fused prep: cvt x, cvt weights, vimp
// vimp: ONE pass over v_ema (wave per s-row, all 16 heads accumulated in-reg).
__global__ __launch_bounds__(256) void prep_kernel(
    const float* __restrict__ x,
    const float* __restrict__ Wq, const float* __restrict__ Wk,
    const float* __restrict__ Wv, const float* __restrict__ Wo,
    const float* __restrict__ v_ema,
    const float* __restrict__ Wimp, const float* __restrict__ bimp,
    __bf16* __restrict__ x_bf, __bf16* __restrict__ wq_bf, __bf16* __restrict__ wk_bf,
    __bf16* __restrict__ wv_bf, __bf16* __restrict__ wo_bf,
    float* __restrict__ vimp) {
  const int bid = blockIdx.x;
  const int tid = threadIdx.x;
  if (bid < 4096) {                       // x: 4M floats = 1M float4
    int i = bid * 256 + tid;
    float4 v = ((const float4*)x)[i];
    bf16x4 o; o[0] = (__bf16)v.x; o[1] = (__bf16)v.y; o[2] = (__bf16)v.z; o[3] = (__bf16)v.w;
    ((bf16x4*)x_bf)[i] = o;
  } else if (bid < 8192) {                // 4 weight mats: 4 x 256K float4
    int i = (bid - 4096) * 256 + tid;
    int sel = i >> 18;
    int j = i & 262143;
    const float* s = (sel == 0) ? Wq : (sel == 1) ? Wk : (sel == 2) ? Wv : Wo;
    __bf16* d      = (sel == 0) ? wq_bf : (sel == 1) ? wk_bf : (sel == 2) ? wv_bf : wo_bf;
    float4 v = ((const float4*)s)[j];
    bf16x4 o; o[0] = (__bf16)v.x; o[1] = (__bf16)v.y; o[2] = (__bf16)v.z; o[3] = (__bf16)v.w;
    ((bf16x4*)d)[j] = o;
  } else {                                // vimp: one wave per s, all 16 heads
    const int s    = (bid - 8192) * 4 + (tid >> 6);
    const int lane = tid & 63;
    const float4* ve = (const float4*)(v_ema + (size_t)s * D_MODEL);
    float acc0 = 0.f, acc1 = 0.f, acc2 = 0.f, acc3 = 0.f;
    float acc4 = 0.f, acc5 = 0.f, acc6 = 0.f, acc7 = 0.f;
    float acc8 = 0.f, acc9 = 0.f, accA = 0.f, accB = 0.f;
    float accC = 0.f, accD = 0.f, accE = 0.f, accF = 0.f;
    #pragma unroll
    for (int i = 0; i < 4; i++) {
      const int c = lane + i * 64;                 // float4 index within the row
      float4 v = ve[c];
      #define VIMP_H(H, ACC)                                                     \
        {                                                                        \
          float4 w = ((const float4*)(Wimp + (H) * D_MODEL))[c];                 \
          ACC += v.x * w.x + v.y * w.y + v.z * w.z + v.w * w.w;                  \
        }
      VIMP_H(0, acc0)  VIMP_H(1, acc1)  VIMP_H(2, acc2)  VIMP_H(3, acc3)
      VIMP_H(4, acc4)  VIMP_H(5, acc5)  VIMP_H(6, acc6)  VIMP_H(7, acc7)
      VIMP_H(8, acc8)  VIMP_H(9, acc9)  VIMP_H(10, accA) VIMP_H(11, accB)
      VIMP_H(12, accC) VIMP_H(13, accD) VIMP_H(14, accE) VIMP_H(15, accF)
      #undef VIMP_H
    }
    #define VIMP_RED(ACC)                                                        \
      for (int mm = 32; mm >= 1; mm >>= 1) ACC += __shfl_xor(ACC, mm);
    VIMP_RED(acc0) VIMP_RED(acc1) VIMP_RED(acc2) VIMP_RED(acc3)
    VIMP_RED(acc4) VIMP_RED(acc5) VIMP_RED(acc6) VIMP_RED(acc7)
    VIMP_RED(acc8) VIMP_RED(acc9) VIMP_RED(accA) VIMP_RED(accB)
    VIMP_RED(accC) VIMP_RED(accD) VIMP_RED(accE) VIMP_RED(accF)
    #undef VIMP_RED
    if (lane == 0) {
      vimp[0  * SEQ + s] = acc0 + bimp[0];  vimp[1  * SEQ + s] = acc1 + bimp[1];
      vimp[2  * SEQ + s] = acc2 + bimp[2];  vimp[3  * SEQ + s] = acc3 + bimp[3];
      vimp[4  * SEQ + s] = acc4 + bimp[4];  vimp[5  * SEQ + s] = acc5 + bimp[5];
      vimp[6  * SEQ + s] = acc6 + bimp[6];  vimp[7  * SEQ + s] = acc7 + bimp[7];
      vimp[8  * SEQ + s] = acc8 + bimp[8];  vimp[9  * SEQ + s] = acc9 + bimp[9];
      vimp[10 * SEQ + s] = accA + bimp[10]; vimp[11 * SEQ + s] = accB + bimp[11];
      vimp[12 * SEQ + s] = accC + bimp[12]; vimp[13 * SEQ + s] = accD + bimp[13];
      vimp[14 * SEQ + s] = accE + bimp[14]; vimp[15 * SEQ + s] = accF + bimp[15];
    }
  }
}

// ---------------------------------------------------- MERGED QKV: W direct-to-register
// R9 structure (128x64 tiles x 3 outputs, 512 blocks, 2/CU) with W moved OUT of LDS:
// each W frag is consumed by exactly one wave, so the LDS round-trip (DMA write +
// ds_read) was pure overhead (24KB of the 40KB/iter LDS staging). Now each thread
// direct-loads next iter's 12 W frags (16B each; quads cover 4x16B contiguous = clean
// 64B L2 segments) into double-buffered registers, issued a full iteration early
// (~1200cy cover >> 300cy L2 latency). A stays global_load_lds (multi-wave shared).
// Ledger: at wait, outstanding = A(t)4+W(t)12+A(t+1)4+W(t+1)12 = 32; vmcnt(16)
// retires exactly A(t)+W(t). LDS 80KB -> 32KB; DMA calls/iter 10 -> 4.
//   Q (z0): normal product, scalar bf16 stores, pre-scaled by QSC
//   K (z1): TRANSPOSED product, Kp[bh][key][64], col' = (col+(key&7)*8)&63
//   V (z2): normal product, Vp[bh][key>>6][d][64], key' = (key+(d&7)*8)&63
__global__ __launch_bounds__(256) void gemm_qkv(
    const __bf16* __restrict__ A,
    const __bf16* __restrict__ Wq, const __bf16* __restrict__ Wk, const __bf16* __restrict__ Wv,
    const float* __restrict__ bq, const float* __restrict__ bk, const float* __restrict__ bv,
    __bf16* __restrict__ qo, __bf16* __restrict__ kp, __bf16* __restrict__ vp) {
  // bijective XCD swizzle: id 0..511; xcd=id&7, j=id>>3; by=(j&3)*8+xcd, bx=j>>2
  const int id = blockIdx.x + (blockIdx.y << 4);
  const int xcd = id & 7;
  const int j = id >> 3;
  const int by = (j & 3) * 8 + xcd;      // 0..31 row panel
  const int bx = j >> 2;                 // 0..15 col panel (64-wide = one head window)

  __shared__ __bf16 As[2 * 8192];        // 2 x 128 rows x 64 k   (32 KB)

  const int tid = threadIdx.x;
  const int w = tid >> 6, l = tid & 63;
  const int quad = l >> 4, l16 = l & 15;
  const int wy = w >> 1, wx = w & 1;
  const int row0 = by * 128;
  const int col0 = bx * 64;

  const f32x4 fzero = {0.f, 0.f, 0.f, 0.f};
  f32x4 aq[4][2], ak[4][2], av[4][2];
  #pragma unroll
  for (int i = 0; i < 4; i++)
    #pragma unroll
    for (int jj = 0; jj < 2; jj++) { aq[i][jj] = fzero; ak[i][jj] = fzero; av[i][jj] = fzero; }

  const int rk = tid >> 3;                       // 0..31
  const int csw = (((tid & 7) ^ (rk & 7)) * 8);
  const int tid8 = tid * 8;
  const __bf16* aS = A + (size_t)(row0 + rk) * D_MODEL + csw;

  // W direct-load bases: thread covers rows col0+wx*32+{0,16}+l16, chunk (ks*4+quad)*8
  // (linear chunks: no XOR needed from global; quads give contiguous 64B per row)
  const size_t wrow0 = (size_t)(col0 + wx * 32 + l16) * D_MODEL + quad * 8;
  const __bf16* qW = Wq + wrow0;
  const __bf16* kW = Wk + wrow0;
  const __bf16* vW = Wv + wrow0;
  // frag index f = mat*4 + ni*2 + ks; offset = ni*16*1024 + ks*32 (+ t*64)

  const int pch0 = ((0 * 4 + quad) ^ (l16 & 7)) * 8;
  const int pch1 = ((1 * 4 + quad) ^ (l16 & 7)) * 8;

  bf16x8 wf[2][12];
  #define WLOAD(BUF, KT)                                                          \
    _Pragma("unroll") for (int ni = 0; ni < 2; ++ni)                              \
      _Pragma("unroll") for (int ks = 0; ks < 2; ++ks) {                          \
        const size_t off = (size_t)ni * 16 * D_MODEL + ks * 32 + (size_t)(KT) * 64; \
        wf[BUF][0 + ni * 2 + ks] = *(const bf16x8*)(qW + off);                    \
        wf[BUF][4 + ni * 2 + ks] = *(const bf16x8*)(kW + off);                    \
        wf[BUF][8 + ni * 2 + ks] = *(const bf16x8*)(vW + off);                    \
      }

  // prologue: A(0) DMA + W(0) register loads
  #pragma unroll
  for (int p = 0; p < 4; ++p)
    async16(&As[p * 2048 + tid8], aS + (size_t)p * 32 * D_MODEL);
  WLOAD(0, 0)

  #pragma unroll 2
  for (int t = 0; t < 16; ++t) {
    const int rbA = (t & 1) << 13;
    const int cb = t & 1, nbuf = cb ^ 1;
    if (t < 15) {                                // stage A(t+1) + load W(t+1), counted wait
      const size_t kk = (size_t)(t + 1) * 64;
      #pragma unroll
      for (int p = 0; p < 4; ++p)
        async16(&As[((t + 1) & 1) * 8192 + p * 2048 + tid8], aS + (size_t)p * 32 * D_MODEL + kk);
      WLOAD(nbuf, t + 1)
      asm volatile("s_waitcnt vmcnt(16)" ::: "memory");  // A(t)+W(t) landed; t+1 in flight
    } else {
      asm volatile("s_waitcnt vmcnt(0)" ::: "memory");
    }
    __builtin_amdgcn_s_barrier();
    #pragma unroll
    for (int ks = 0; ks < 2; ++ks) {
      const int pch = ks ? pch1 : pch0;
      bf16x8 af[4];
      #pragma unroll
      for (int mi = 0; mi < 4; mi++)
        af[mi] = *(const bf16x8*)&As[rbA + (wy * 64 + mi * 16 + l16) * 64 + pch];
      #pragma unroll
      for (int mi = 0; mi < 4; mi++)
        #pragma unroll
        for (int ni = 0; ni < 2; ni++) {
          aq[mi][ni] = mfma16(af[mi], wf[cb][0 + ni * 2 + ks], aq[mi][ni]);
          ak[mi][ni] = mfma16(wf[cb][4 + ni * 2 + ks], af[mi], ak[mi][ni]);  // transposed
          av[mi][ni] = mfma16(af[mi], wf[cb][8 + ni * 2 + ks], av[mi][ni]);
        }
    }
    __builtin_amdgcn_s_barrier();
  }

  // ---------------- Q epilogue (scalar stores, pre-scaled)
  #pragma unroll
  for (int ni = 0; ni < 2; ni++) {
    const int col = col0 + wx * 32 + ni * 16 + l16;
    const float bqv = bq[col];
    #pragma unroll
    for (int mi = 0; mi < 4; mi++) {
      const int row = row0 + wy * 64 + mi * 16 + quad * 4;
      #pragma unroll
      for (int r = 0; r < 4; r++)
        qo[(size_t)(row + r) * D_MODEL + col] = (__bf16)((aq[mi][ni][r] + bqv) * QSC);
    }
  }
  // ---------------- K epilogue (transposed frags -> packed + rotated)
  #pragma unroll
  for (int ni = 0; ni < 2; ni++) {
    const int wcolbase = col0 + wx * 32 + ni * 16 + quad * 4;
    const float4 b4 = *(const float4*)&bk[wcolbase];
    const float bb[4] = {b4.x, b4.y, b4.z, b4.w};
    #pragma unroll
    for (int mi = 0; mi < 4; mi++) {
      const int token = row0 + wy * 64 + mi * 16 + l16;
      const int bh = (token >> 10) * 16 + (wcolbase >> 6);
      const int colp = ((wcolbase & 63) + ((token & 7) << 3)) & 63;   // rotation
      union { __bf16 hh[4]; uint2 uu; } pk;
      #pragma unroll
      for (int r = 0; r < 4; r++) pk.hh[r] = (__bf16)(ak[mi][ni][r] + bb[r]);
      *(uint2*)(kp + ((size_t)bh * SEQ + (token & 1023)) * HD + colp) = pk.uu;
    }
  }
  // ---------------- V epilogue (chunk-packed + rotated)
  #pragma unroll
  for (int ni = 0; ni < 2; ni++) {
    const int col = col0 + wx * 32 + ni * 16 + l16;            // d (model dim)
    const float bvv = bv[col];
    #pragma unroll
    for (int mi = 0; mi < 4; mi++) {
      const int token = row0 + wy * 64 + mi * 16 + quad * 4;
      const int bh = (token >> 10) * 16 + (col >> 6);
      const int chk = (token >> 6) & 15;
      const int keyp = ((token & 63) + ((col & 7) << 3)) & 63;          // rotation
      const size_t base = (((size_t)bh * 16 + chk) * 64 + (col & 63)) * 64 + keyp;
      union { __bf16 hh[4]; uint2 uu; } pk;
      #pragma unroll
      for (int r = 0; r < 4; r++) pk.hh[r] = (__bf16)(av[mi][ni][r] + bvv);
      *(uint2*)(vp + base) = pk.uu;
    }
  }
  #undef WLOAD
}

// ---------------------------------------------------- O-proj: 128x64 tiles, 512 blocks (R8)
__global__ __launch_bounds__(256) void gemm_o(
    const __bf16* __restrict__ A, const __bf16* __restrict__ W,
    const float* __restrict__ bias, float* __restrict__ out) {
  // bijective XCD swizzle: id 0..511; xcd=id&7, j=id>>3; by=(j&3)*8+xcd, bx=j>>2
  const int id = blockIdx.x + (blockIdx.y << 4);
  const int xcd = id & 7;
  const int j = id >> 3;
  const int by = (j & 3) * 8 + xcd;
  const int bx = j >> 2;                 // 0..15

  __shared__ __bf16 As[2 * 8192];        // 2 x 128 rows x 64 k  (32 KB)
  __shared__ __bf16 Bs[2 * 4096];        // 2 x  64 rows x 64 k  (16 KB)

  const int tid = threadIdx.x;
  const int w = tid >> 6, l = tid & 63;
  const int quad = l >> 4, l16 = l & 15;
  const int wy = w >> 1, wx = w & 1;
  const int row0 = by * 128;
  const int col0 = bx * 64;

  const f32x4 fzero = {0.f, 0.f, 0.f, 0.f};
  f32x4 acc[4][2];
  for (int i = 0; i < 4; i++)
    for (int jj = 0; jj < 2; jj++) acc[i][jj] = fzero;

  const int rk = tid >> 3;                       // 0..31
  const int csw = (((tid & 7) ^ (rk & 7)) * 8);
  const int tid8 = tid * 8;
  const __bf16* aS = A + (size_t)(row0 + rk) * D_MODEL + csw;
  const __bf16* bS = W + (size_t)(col0 + rk) * D_MODEL + csw;

  const int pch0 = ((0 * 4 + quad) ^ (l16 & 7)) * 8;
  const int pch1 = ((1 * 4 + quad) ^ (l16 & 7)) * 8;

  // prologue: stage K-tile 0 (A: 4 calls, B: 2 calls)
  #pragma unroll
  for (int p = 0; p < 4; ++p)
    async16(&As[p * 2048 + tid8], aS + (size_t)p * 32 * D_MODEL);
  #pragma unroll
  for (int p = 0; p < 2; ++p)
    async16(&Bs[p * 2048 + tid8], bS + (size_t)p * 32 * D_MODEL);

  #pragma unroll 2
  for (int t = 0; t < 16; ++t) {
    const int rbA = (t & 1) << 13;
    const int rbB = (t & 1) << 12;
    if (t < 15) {
      const int sbA = ((t + 1) & 1) << 13;
      const int sbB = ((t + 1) & 1) << 12;
      const size_t kk = (size_t)(t + 1) * 64;
      #pragma unroll
      for (int p = 0; p < 4; ++p)
        async16(&As[sbA + p * 2048 + tid8], aS + (size_t)p * 32 * D_MODEL + kk);
      #pragma unroll
      for (int p = 0; p < 2; ++p)
        async16(&Bs[sbB + p * 2048 + tid8], bS + (size_t)p * 32 * D_MODEL + kk);
      asm volatile("s_waitcnt vmcnt(6)" ::: "memory");   // tile t landed; t+1 in flight
    } else {
      asm volatile("s_waitcnt vmcnt(0)" ::: "memory");
    }
    __builtin_amdgcn_s_barrier();
    #pragma unroll
    for (int ks = 0; ks < 2; ++ks) {
      const int pch = ks ? pch1 : pch0;
      bf16x8 af[4], bfr[2];
      #pragma unroll
      for (int mi = 0; mi < 4; mi++) af[mi]  = *(const bf16x8*)&As[rbA + (wy * 64 + mi * 16 + l16) * 64 + pch];
      #pragma unroll
      for (int ni = 0; ni < 2; ni++) bfr[ni] = *(const bf16x8*)&Bs[rbB + (wx * 32 + ni * 16 + l16) * 64 + pch];
      #pragma unroll
      for (int mi = 0; mi < 4; mi++)
        #pragma unroll
        for (int ni = 0; ni < 2; ni++)
          acc[mi][ni] = mfma16(af[mi], bfr[ni], acc[mi][ni]);
    }
    __builtin_amdgcn_s_barrier();
  }

  #pragma unroll
  for (int ni = 0; ni < 2; ni++) {
    const int col = col0 + wx * 32 + ni * 16 + l16;
    const float bv = bias[col];
    #pragma unroll
    for (int mi = 0; mi < 4; mi++) {
      const int row = row0 + wy * 64 + mi * 16 + quad * 4;
      #pragma unroll
      for (int r = 0; r < 4; r++)
        out[(size_t)(row + r) * D_MODEL + col] = acc[mi][ni][r] + bv;
    }
  }
}

// ------------------------------------------------------- attention, MERGED SWEEP
// R7 structure + gg-balance remap: pass count per block = 16-gg (16..9). Co-resident
// pairs (id, id+256) had gg pairs (g, g+4) -> 28 vs 22 total passes (+-12% critical-
// path imbalance). Remap gg ^= (gg&4)?3:0 -> pairs (0,7),(1,6),(2,5),(3,4), all 25.
__global__ __launch_bounds__(256, 2) void attn_kernel(
    const __bf16* __restrict__ Qb, const __bf16* __restrict__ Kp,
    const __bf16* __restrict__ Vp, const float* __restrict__ vimp,
    __bf16* __restrict__ Ob) {
  const int id = blockIdx.x;
  const int bh = id & 63;
  const int ggi = id >> 6;                // 0..7
  const int gg = ggi ^ ((ggi & 4) ? 3 : 0);   // balance co-resident pass counts
  const int b = bh >> 4, h = bh & 15;
  const int tid = threadIdx.x;
  const int wave = tid >> 6, lane = tid & 63;
  const int quad = lane >> 4, l16 = lane & 15;

  __shared__ __bf16 Kl[3][4096];          // 64 keys x 64 dims (rotated rows)
  __shared__ __bf16 Vl[3][4096];          // 64 dims x 64 keys (rotated rows)
  __shared__ __bf16 Ps[4][16][72];

  const __bf16* kbase = Kp + (size_t)bh * (SEQ * HD);
  const __bf16* vbase = Vp + (size_t)bh * (SEQ * HD);
  const float* vimpH = vimp + h * SEQ;

  const int rot0 = ((quad + (l16 & 7)) & 7) * 8;        // logical cols quad*8..+7
  const int rot1 = ((quad + 4 + (l16 & 7)) & 7) * 8;    // logical cols 32+quad*8..+7
  const int frow = l16 * 64;

  const int g0 = gg, g1 = 15 - gg;        // g0 < g1 always (7 < 8)

  const int qrow0 = g0 * 64 + wave * 16 + l16;
  const int qrow1 = g1 * 64 + wave * 16 + l16;
  const __bf16* qp0 = Qb + (size_t)(b * SEQ + qrow0) * D_MODEL + h * HD;
  const __bf16* qp1 = Qb + (size_t)(b * SEQ + qrow1) * D_MODEL + h * HD;
  bf16x8 qA0 = *(const bf16x8*)(qp0 + quad * 8);        // Q pre-scaled by QSC in gemm
  bf16x8 qA1 = *(const bf16x8*)(qp0 + 32 + quad * 8);
  bf16x8 qB0 = *(const bf16x8*)(qp1 + quad * 8);
  bf16x8 qB1 = *(const bf16x8*)(qp1 + 32 + quad * 8);

  // prologue: DMA chunks 0 and 1
  async16(&Kl[0][tid * 8], kbase + tid * 8);
  async16(&Kl[0][2048 + tid * 8], kbase + 2048 + tid * 8);
  async16(&Vl[0][tid * 8], vbase + tid * 8);
  async16(&Vl[0][2048 + tid * 8], vbase + 2048 + tid * 8);
  async16(&Kl[1][tid * 8], kbase + 4096 + tid * 8);
  async16(&Kl[1][2048 + tid * 8], kbase + 4096 + 2048 + tid * 8);
  async16(&Vl[1][tid * 8], vbase + 4096 + tid * 8);
  async16(&Vl[1][2048 + tid * 8], vbase + 4096 + 2048 + tid * 8);

  float l0 = 0.f, l1 = 0.f;
  f32x4 o0[4], o1[4];
  #pragma unroll
  for (int td = 0; td < 4; td++) {
    o0[td][0] = 0.f; o0[td][1] = 0.f; o0[td][2] = 0.f; o0[td][3] = 0.f;
    o1[td][0] = 0.f; o1[td][1] = 0.f; o1[td][2] = 0.f; o1[td][3] = 0.f;
  }

  #pragma unroll 1
  for (int c = 0; c <= g1; ++c) {
    const int buf = c % 3;
    if (c < g1) asm volatile("s_waitcnt vmcnt(4)" ::: "memory");
    else        asm volatile("s_waitcnt vmcnt(0)" ::: "memory");
    __builtin_amdgcn_s_barrier();
    const int kc = c * 64;
    // vi(c) first (its compiler wait will count DMA(c+2) behind it -> vmcnt(4))
    float4 vi[4];
    #pragma unroll
    for (int t = 0; t < 4; t++) vi[t] = *(const float4*)(vimpH + kc + t * 16 + quad * 4);
    __builtin_amdgcn_sched_barrier(0);
    if (c + 2 <= g1) {                    // DMA chunk c+2 into buf (c+2)%3
      const int nb = (c + 2) % 3;
      const __bf16* gk = kbase + (size_t)(c + 2) * 4096;
      const __bf16* gv = vbase + (size_t)(c + 2) * 4096;
      async16(&Kl[nb][tid * 8], gk + tid * 8);
      async16(&Kl[nb][2048 + tid * 8], gk + 2048 + tid * 8);
      async16(&Vl[nb][tid * 8], gv + tid * 8);
      async16(&Vl[nb][2048 + tid * 8], gv + 2048 + tid * 8);
    }
    __builtin_amdgcn_sched_barrier(0);

    bf16x8 kf0[4], kf1[4], vfr0[4], vfr1[4];
    #pragma unroll
    for (int t = 0; t < 4; t++) {
      kf0[t] = *(const bf16x8*)&Kl[buf][t * 1024 + frow + rot0];
      kf1[t] = *(const bf16x8*)&Kl[buf][t * 1024 + frow + rot1];
    }
    #pragma unroll
    for (int td = 0; td < 4; td++) {
      vfr0[td] = *(const bf16x8*)&Vl[buf][td * 1024 + frow + rot0];
      vfr1[td] = *(const bf16x8*)&Vl[buf][td * 1024 + frow + rot1];
    }
    const f32x4 fz = {0.f, 0.f, 0.f, 0.f};

    // ---------------- tile1 (rows qrow1): active every pass
    {
      f32x4 sacc[4];
      __builtin_amdgcn_s_setprio(1);
      #pragma unroll
      for (int t = 0; t < 4; t++) {
        sacc[t] = mfma16(kf0[t], qB0, fz);
        sacc[t] = mfma16(kf1[t], qB1, sacc[t]);
      }
      __builtin_amdgcn_s_setprio(0);
      float p[4][4];
      float lsum = 0.f;
      #pragma unroll
      for (int t = 0; t < 4; t++) {
        const float vib[4] = {vi[t].x, vi[t].y, vi[t].z, vi[t].w};
        if (c == g1) {
          #pragma unroll
          for (int r = 0; r < 4; r++) {
            float pp = fexp2(sacc[t][r] + BSC * vib[r]);
            pp = (kc + t * 16 + quad * 4 + r <= qrow1) ? pp : 0.f;
            p[t][r] = pp;
            lsum += pp;
          }
        } else {
          #pragma unroll
          for (int r = 0; r < 4; r++) {
            float pp = fexp2(sacc[t][r] + BSC * vib[r]);
            p[t][r] = pp;
            lsum += pp;
          }
        }
      }
      l1 += lsum;
      #pragma unroll
      for (int t = 0; t < 4; t++) {
        union { __bf16 hh[4]; uint2 uu; } pk;
        #pragma unroll
        for (int r = 0; r < 4; r++) pk.hh[r] = (__bf16)p[t][r];
        *(uint2*)&Ps[wave][l16][t * 16 + quad * 4] = pk.uu;
      }
      bf16x8 pf0 = *(const bf16x8*)&Ps[wave][l16][quad * 8];
      bf16x8 pf1 = *(const bf16x8*)&Ps[wave][l16][32 + quad * 8];
      __builtin_amdgcn_s_setprio(1);
      #pragma unroll
      for (int td = 0; td < 4; td++) {
        o1[td] = mfma16(vfr0[td], pf0, o1[td]);
        o1[td] = mfma16(vfr1[td], pf1, o1[td]);
      }
      __builtin_amdgcn_s_setprio(0);
    }

    // ---------------- tile0 (rows qrow0): active while c <= g0 (block-uniform)
    if (c <= g0) {
      f32x4 sacc[4];
      __builtin_amdgcn_s_setprio(1);
      #pragma unroll
      for (int t = 0; t < 4; t++) {
        sacc[t] = mfma16(kf0[t], qA0, fz);
        sacc[t] = mfma16(kf1[t], qA1, sacc[t]);
      }
      __builtin_amdgcn_s_setprio(0);
      float p[4][4];
      float lsum = 0.f;
      #pragma unroll
      for (int t = 0; t < 4; t++) {
        const float vib[4] = {vi[t].x, vi[t].y, vi[t].z, vi[t].w};
        if (c == g0) {
          #pragma unroll
          for (int r = 0; r < 4; r++) {
            float pp = fexp2(sacc[t][r] + BSC * vib[r]);
            pp = (kc + t * 16 + quad * 4 + r <= qrow0) ? pp : 0.f;
            p[t][r] = pp;
            lsum += pp;
          }
        } else {
          #pragma unroll
          for (int r = 0; r < 4; r++) {
            float pp = fexp2(sacc[t][r] + BSC * vib[r]);
            p[t][r] = pp;
            lsum += pp;
          }
        }
      }
      l0 += lsum;
      #pragma unroll
      for (int t = 0; t < 4; t++) {
        union { __bf16 hh[4]; uint2 uu; } pk;
        #pragma unroll
        for (int r = 0; r < 4; r++) pk.hh[r] = (__bf16)p[t][r];
        *(uint2*)&Ps[wave][l16][t * 16 + quad * 4] = pk.uu;
      }
      bf16x8 pf0 = *(const bf16x8*)&Ps[wave][l16][quad * 8];
      bf16x8 pf1 = *(const bf16x8*)&Ps[wave][l16][32 + quad * 8];
      __builtin_amdgcn_s_setprio(1);
      #pragma unroll
      for (int td = 0; td < 4; td++) {
        o0[td] = mfma16(vfr0[td], pf0, o0[td]);
        o0[td] = mfma16(vfr1[td], pf1, o0[td]);
      }
      __builtin_amdgcn_s_setprio(0);
      if (c == g0) {                      // tile0 complete: write out
        float L = l0;
        L += __shfl_xor(L, 16);
        L += __shfl_xor(L, 32);
        const float il = 1.0f / L;
        __bf16* op = Ob + (size_t)(b * SEQ + qrow0) * D_MODEL + h * HD;
        #pragma unroll
        for (int td = 0; td < 4; td++) {
          union { __bf16 hh[4]; uint2 uu; } pk;
          #pragma unroll
          for (int r = 0; r < 4; r++) pk.hh[r] = (__bf16)(o0[td][r] * il);
          *(uint2*)(op + td * 16 + quad * 4) = pk.uu;
        }
      }
    }
  }

  // tile1 epilogue
  float L = l1;
  L += __shfl_xor(L, 16);
  L += __shfl_xor(L, 32);
  const float il = 1.0f / L;
  __bf16* op = Ob + (size_t)(b * SEQ + qrow1) * D_MODEL + h * HD;
  #pragma unroll
  for (int td = 0; td < 4; td++) {
    union { __bf16 hh[4]; uint2 uu; } pk;
    #pragma unroll
    for (int r = 0; r < 4; r++) pk.hh[r] = (__bf16)(o1[td][r] * il);
    *(uint2*)(op + td * 16 + quad * 4) = pk.uu;
  }
}

// ---------------------------------------------------------------------------
extern "C" void kernel_launch(void* const* d_in, const int* in_sizes, int n_in,
                              void* d_out, int out_size, void* d_ws, size_t ws_size,
                              hipStream_t stream) {
  const float* x     = (const float*)d_in[0];
  const float* Wq    = (const float*)d_in[1];
  const float* bq    = (const float*)d_in[2];
  const float* Wk    = (const float*)d_in[3];
  const float* bk    = (const float*)d_in[4];
  const float* Wv    = (const float*)d_in[5];
  const float* bv    = (const float*)d_in[6];
  const float* Wo    = (const float*)d_in[7];
  const float* bo    = (const float*)d_in[8];
  const float* Wimp  = (const float*)d_in[9];
  const float* bimp  = (const float*)d_in[10];
  // d_in[11] = k_ema (unused: kimp bias is per-q-row constant, cancels in softmax)
  const float* v_ema = (const float*)d_in[12];
  float* out = (float*)d_out;

  char* ws = (char*)d_ws;
  __bf16* x_bf  = (__bf16*)(ws);                        // 8 MB
  __bf16* wq_bf = (__bf16*)(ws + (8ull  << 20));        // 2 MB each
  __bf16* wk_bf = (__bf16*)(ws + (10ull << 20));
  __bf16* wv_bf = (__bf16*)(ws + (12ull << 20));
  __bf16* wo_bf = (__bf16*)(ws + (14ull << 20));
  __bf16* q_bf  = (__bf16*)(ws + (16ull << 20));        // 8 MB each
  __bf16* kp_bf = (__bf16*)(ws + (24ull << 20));        // K packed+rotated [bh][key][64]
  __bf16* vp_bf = (__bf16*)(ws + (32ull << 20));        // V packed+rotated [bh][ch][d][64]
  __bf16* a_bf  = (__bf16*)(ws + (40ull << 20));
  float*  vimp  = (float*)(ws + (48ull << 20));         // 64 KB

  prep_kernel<<<8448, 256, 0, stream>>>(
      x, Wq, Wk, Wv, Wo, v_ema, Wimp, bimp,
      x_bf, wq_bf, wk_bf, wv_bf, wo_bf, vimp);

  // MERGED Q,K,V projections: A via LDS, W direct-to-register (double-buffered).
  gemm_qkv<<<dim3(16, 32), 256, 0, stream>>>(
      x_bf, wq_bf, wk_bf, wv_bf, bq, bk, bv, q_bf, kp_bf, vp_bf);

  attn_kernel<<<dim3(512), 256, 0, stream>>>(
      q_bf, kp_bf, vp_bf, vimp, a_bf);

  // O-projection: 128x64 tiles, 512 blocks -> 2 blocks/CU co-resident
  gemm_o<<<dim3(16, 32), 256, 0, stream>>>(a_bf, wo_bf, bo, out);
}

// Round 11
// 179.786 us; speedup vs baseline: 1.6348x; 1.6348x over previous
//
#include <hip/hip_runtime.h>
#include <hip/hip_bf16.h>
#include <math.h>

#define D_MODEL 1024
#define SEQ     1024
#define BATCH   4
#define NHEADS  16
#define HD      64

// log2(e) folds: p = exp2(s') with s' = (q.k)*0.125*log2e + 0.05*log2e*vimp
// (kimp term is constant per q-row -> cancels in softmax; dropped entirely)
#define QSC 0.18033688f   // 0.125 * log2(e)
#define BSC 0.072134752f  // 0.05  * log2(e)

typedef __bf16 bf16x8 __attribute__((ext_vector_type(8)));
typedef __bf16 bf16x4 __attribute__((ext_vector_type(4)));
typedef float  f32x4  __attribute__((ext_vector_type(4)));

__device__ __forceinline__ f32x4 mfma16(bf16x8 a, bf16x8 b, f32x4 c) {
  return __builtin_amdgcn_mfma_f32_16x16x32_bf16(a, b, c, 0, 0, 0);
}

// async global->LDS, 16B per lane; LDS dest = wave-uniform base + lane*16
__device__ __forceinline__ void async16(__bf16* lds, const __bf16* g) {
  __builtin_amdgcn_global_load_lds(g, lds, 16, 0, 0);
}

// raw v_exp_f32: args here are bounded (|x| < ~60); flush-to-zero below -126 is
// exactly right for softmax. Skips libm's range-fixup VALU around each call.
__device__ __forceinline__ float fexp2(float x) {
  float r;
  asm volatile("v_exp_f32 %0, %1" : "=v"(r) : "v"(x));
  return r;
}

// ------------------------------------------ fused prep: cvt x, cvt weights, vimp
// vimp: ONE pass over v_ema (wave per s-row, all 16 heads accumulated in-reg).
__global__ __launch_bounds__(256) void prep_kernel(
    const float* __restrict__ x,
    const float* __restrict__ Wq, const float* __restrict__ Wk,
    const float* __restrict__ Wv, const float* __restrict__ Wo,
    const float* __restrict__ v_ema,
    const float* __restrict__ Wimp, const float* __restrict__ bimp,
    __bf16* __restrict__ x_bf, __bf16* __restrict__ wq_bf, __bf16* __restrict__ wk_bf,
    __bf16* __restrict__ wv_bf, __bf16* __restrict__ wo_bf,
    float* __restrict__ vimp) {
  const int bid = blockIdx.x;
  const int tid = threadIdx.x;
  if (bid < 4096) {                       // x: 4M floats = 1M float4
    int i = bid * 256 + tid;
    float4 v = ((const float4*)x)[i];
    bf16x4 o; o[0] = (__bf16)v.x; o[1] = (__bf16)v.y; o[2] = (__bf16)v.z; o[3] = (__bf16)v.w;
    ((bf16x4*)x_bf)[i] = o;
  } else if (bid < 8192) {                // 4 weight mats: 4 x 256K float4
    int i = (bid - 4096) * 256 + tid;
    int sel = i >> 18;
    int j = i & 262143;
    const float* s = (sel == 0) ? Wq : (sel == 1) ? Wk : (sel == 2) ? Wv : Wo;
    __bf16* d      = (sel == 0) ? wq_bf : (sel == 1) ? wk_bf : (sel == 2) ? wv_bf : wo_bf;
    float4 v = ((const float4*)s)[j];
    bf16x4 o; o[0] = (__bf16)v.x; o[1] = (__bf16)v.y; o[2] = (__bf16)v.z; o[3] = (__bf16)v.w;
    ((bf16x4*)d)[j] = o;
  } else {                                // vimp: one wave per s, all 16 heads
    const int s    = (bid - 8192) * 4 + (tid >> 6);
    const int lane = tid & 63;
    const float4* ve = (const float4*)(v_ema + (size_t)s * D_MODEL);
    float acc0 = 0.f, acc1 = 0.f, acc2 = 0.f, acc3 = 0.f;
    float acc4 = 0.f, acc5 = 0.f, acc6 = 0.f, acc7 = 0.f;
    float acc8 = 0.f, acc9 = 0.f, accA = 0.f, accB = 0.f;
    float accC = 0.f, accD = 0.f, accE = 0.f, accF = 0.f;
    #pragma unroll
    for (int i = 0; i < 4; i++) {
      const int c = lane + i * 64;                 // float4 index within the row
      float4 v = ve[c];
      #define VIMP_H(H, ACC)                                                     \
        {                                                                        \
          float4 w = ((const float4*)(Wimp + (H) * D_MODEL))[c];                 \
          ACC += v.x * w.x + v.y * w.y + v.z * w.z + v.w * w.w;                  \
        }
      VIMP_H(0, acc0)  VIMP_H(1, acc1)  VIMP_H(2, acc2)  VIMP_H(3, acc3)
      VIMP_H(4, acc4)  VIMP_H(5, acc5)  VIMP_H(6, acc6)  VIMP_H(7, acc7)
      VIMP_H(8, acc8)  VIMP_H(9, acc9)  VIMP_H(10, accA) VIMP_H(11, accB)
      VIMP_H(12, accC) VIMP_H(13, accD) VIMP_H(14, accE) VIMP_H(15, accF)
      #undef VIMP_H
    }
    #define VIMP_RED(ACC)                                                        \
      for (int mm = 32; mm >= 1; mm >>= 1) ACC += __shfl_xor(ACC, mm);
    VIMP_RED(acc0) VIMP_RED(acc1) VIMP_RED(acc2) VIMP_RED(acc3)
    VIMP_RED(acc4) VIMP_RED(acc5) VIMP_RED(acc6) VIMP_RED(acc7)
    VIMP_RED(acc8) VIMP_RED(acc9) VIMP_RED(accA) VIMP_RED(accB)
    VIMP_RED(accC) VIMP_RED(accD) VIMP_RED(accE) VIMP_RED(accF)
    #undef VIMP_RED
    if (lane == 0) {
      vimp[0  * SEQ + s] = acc0 + bimp[0];  vimp[1  * SEQ + s] = acc1 + bimp[1];
      vimp[2  * SEQ + s] = acc2 + bimp[2];  vimp[3  * SEQ + s] = acc3 + bimp[3];
      vimp[4  * SEQ + s] = acc4 + bimp[4];  vimp[5  * SEQ + s] = acc5 + bimp[5];
      vimp[6  * SEQ + s] = acc6 + bimp[6];  vimp[7  * SEQ + s] = acc7 + bimp[7];
      vimp[8  * SEQ + s] = acc8 + bimp[8];  vimp[9  * SEQ + s] = acc9 + bimp[9];
      vimp[10 * SEQ + s] = accA + bimp[10]; vimp[11 * SEQ + s] = accB + bimp[11];
      vimp[12 * SEQ + s] = accC + bimp[12]; vimp[13 * SEQ + s] = accD + bimp[13];
      vimp[14 * SEQ + s] = accE + bimp[14]; vimp[15 * SEQ + s] = accF + bimp[15];
    }
  }
}

// ---------------------------------------------------- MERGED QKV: R9 EXACT (best: 180.9us)
// 128x64 tiles x 3 outputs, one A-tile stage feeds Q,K,V. 512 blocks = 2/CU.
// LDS 80KB (A 2x16KB + W 3x2x8KB). BK=64, counted vmcnt(10), XOR swizzle, XCD swizzle.
// [R10 ERRATUM: W direct-to-register variant spilled to scratch (wf[cb] runtime index,
//  rule #20 + compiler's 128-VGPR cap) -> 417MB scratch writes, 150us. Reverted.]
//   Q (z0): normal product, scalar bf16 stores, pre-scaled by QSC
//   K (z1): TRANSPOSED product, Kp[bh][key][64], col' = (col+(key&7)*8)&63
//   V (z2): normal product, Vp[bh][key>>6][d][64], key' = (key+(d&7)*8)&63
__global__ __launch_bounds__(256) void gemm_qkv(
    const __bf16* __restrict__ A,
    const __bf16* __restrict__ Wq, const __bf16* __restrict__ Wk, const __bf16* __restrict__ Wv,
    const float* __restrict__ bq, const float* __restrict__ bk, const float* __restrict__ bv,
    __bf16* __restrict__ qo, __bf16* __restrict__ kp, __bf16* __restrict__ vp) {
  // bijective XCD swizzle: id 0..511; xcd=id&7, j=id>>3; by=(j&3)*8+xcd, bx=j>>2
  const int id = blockIdx.x + (blockIdx.y << 4);
  const int xcd = id & 7;
  const int j = id >> 3;
  const int by = (j & 3) * 8 + xcd;      // 0..31 row panel
  const int bx = j >> 2;                 // 0..15 col panel (64-wide = one head window)

  __shared__ __bf16 As[2 * 8192];        // 2 x 128 rows x 64 k   (32 KB)
  __shared__ __bf16 Ws[3][2 * 4096];     // 3 x 2 x 64 rows x 64 k (48 KB)

  const int tid = threadIdx.x;
  const int w = tid >> 6, l = tid & 63;
  const int quad = l >> 4, l16 = l & 15;
  const int wy = w >> 1, wx = w & 1;
  const int row0 = by * 128;
  const int col0 = bx * 64;

  const f32x4 fzero = {0.f, 0.f, 0.f, 0.f};
  f32x4 aq[4][2], ak[4][2], av[4][2];
  #pragma unroll
  for (int i = 0; i < 4; i++)
    #pragma unroll
    for (int jj = 0; jj < 2; jj++) { aq[i][jj] = fzero; ak[i][jj] = fzero; av[i][jj] = fzero; }

  const int rk = tid >> 3;                       // 0..31
  const int csw = (((tid & 7) ^ (rk & 7)) * 8);
  const int tid8 = tid * 8;
  const __bf16* aS = A  + (size_t)(row0 + rk) * D_MODEL + csw;
  const __bf16* qS = Wq + (size_t)(col0 + rk) * D_MODEL + csw;
  const __bf16* kS = Wk + (size_t)(col0 + rk) * D_MODEL + csw;
  const __bf16* vS = Wv + (size_t)(col0 + rk) * D_MODEL + csw;

  const int pch0 = ((0 * 4 + quad) ^ (l16 & 7)) * 8;
  const int pch1 = ((1 * 4 + quad) ^ (l16 & 7)) * 8;

  // prologue: stage K-tile 0 (A: 4 calls, W: 2 calls x 3)
  #pragma unroll
  for (int p = 0; p < 4; ++p)
    async16(&As[p * 2048 + tid8], aS + (size_t)p * 32 * D_MODEL);
  #pragma unroll
  for (int p = 0; p < 2; ++p) {
    async16(&Ws[0][p * 2048 + tid8], qS + (size_t)p * 32 * D_MODEL);
    async16(&Ws[1][p * 2048 + tid8], kS + (size_t)p * 32 * D_MODEL);
    async16(&Ws[2][p * 2048 + tid8], vS + (size_t)p * 32 * D_MODEL);
  }

  #pragma unroll 2
  for (int t = 0; t < 16; ++t) {
    const int rbA = (t & 1) << 13;
    const int rbW = (t & 1) << 12;
    if (t < 15) {                                // stage t+1, counted wait for t
      const int sbA = ((t + 1) & 1) << 13;
      const int sbW = ((t + 1) & 1) << 12;
      const size_t kk = (size_t)(t + 1) * 64;
      #pragma unroll
      for (int p = 0; p < 4; ++p)
        async16(&As[sbA + p * 2048 + tid8], aS + (size_t)p * 32 * D_MODEL + kk);
      #pragma unroll
      for (int p = 0; p < 2; ++p) {
        async16(&Ws[0][sbW + p * 2048 + tid8], qS + (size_t)p * 32 * D_MODEL + kk);
        async16(&Ws[1][sbW + p * 2048 + tid8], kS + (size_t)p * 32 * D_MODEL + kk);
        async16(&Ws[2][sbW + p * 2048 + tid8], vS + (size_t)p * 32 * D_MODEL + kk);
      }
      asm volatile("s_waitcnt vmcnt(10)" ::: "memory");  // tile t landed; t+1 in flight
    } else {
      asm volatile("s_waitcnt vmcnt(0)" ::: "memory");
    }
    __builtin_amdgcn_s_barrier();
    #pragma unroll
    for (int ks = 0; ks < 2; ++ks) {
      const int pch = ks ? pch1 : pch0;
      bf16x8 af[4], qf[2], kf[2], vf[2];
      #pragma unroll
      for (int mi = 0; mi < 4; mi++)
        af[mi] = *(const bf16x8*)&As[rbA + (wy * 64 + mi * 16 + l16) * 64 + pch];
      #pragma unroll
      for (int ni = 0; ni < 2; ni++) {
        const int wrow = (wx * 32 + ni * 16 + l16) * 64 + pch;
        qf[ni] = *(const bf16x8*)&Ws[0][rbW + wrow];
        kf[ni] = *(const bf16x8*)&Ws[1][rbW + wrow];
        vf[ni] = *(const bf16x8*)&Ws[2][rbW + wrow];
      }
      #pragma unroll
      for (int mi = 0; mi < 4; mi++)
        #pragma unroll
        for (int ni = 0; ni < 2; ni++) {
          aq[mi][ni] = mfma16(af[mi], qf[ni], aq[mi][ni]);
          ak[mi][ni] = mfma16(kf[ni], af[mi], ak[mi][ni]);   // transposed product
          av[mi][ni] = mfma16(af[mi], vf[ni], av[mi][ni]);
        }
    }
    __builtin_amdgcn_s_barrier();
  }

  // ---------------- Q epilogue (scalar stores, pre-scaled)
  #pragma unroll
  for (int ni = 0; ni < 2; ni++) {
    const int col = col0 + wx * 32 + ni * 16 + l16;
    const float bqv = bq[col];
    #pragma unroll
    for (int mi = 0; mi < 4; mi++) {
      const int row = row0 + wy * 64 + mi * 16 + quad * 4;
      #pragma unroll
      for (int r = 0; r < 4; r++)
        qo[(size_t)(row + r) * D_MODEL + col] = (__bf16)((aq[mi][ni][r] + bqv) * QSC);
    }
  }
  // ---------------- K epilogue (transposed frags -> packed + rotated)
  #pragma unroll
  for (int ni = 0; ni < 2; ni++) {
    const int wcolbase = col0 + wx * 32 + ni * 16 + quad * 4;
    const float4 b4 = *(const float4*)&bk[wcolbase];
    const float bb[4] = {b4.x, b4.y, b4.z, b4.w};
    #pragma unroll
    for (int mi = 0; mi < 4; mi++) {
      const int token = row0 + wy * 64 + mi * 16 + l16;
      const int bh = (token >> 10) * 16 + (wcolbase >> 6);
      const int colp = ((wcolbase & 63) + ((token & 7) << 3)) & 63;   // rotation
      union { __bf16 hh[4]; uint2 uu; } pk;
      #pragma unroll
      for (int r = 0; r < 4; r++) pk.hh[r] = (__bf16)(ak[mi][ni][r] + bb[r]);
      *(uint2*)(kp + ((size_t)bh * SEQ + (token & 1023)) * HD + colp) = pk.uu;
    }
  }
  // ---------------- V epilogue (chunk-packed + rotated)
  #pragma unroll
  for (int ni = 0; ni < 2; ni++) {
    const int col = col0 + wx * 32 + ni * 16 + l16;            // d (model dim)
    const float bvv = bv[col];
    #pragma unroll
    for (int mi = 0; mi < 4; mi++) {
      const int token = row0 + wy * 64 + mi * 16 + quad * 4;
      const int bh = (token >> 10) * 16 + (col >> 6);
      const int chk = (token >> 6) & 15;
      const int keyp = ((token & 63) + ((col & 7) << 3)) & 63;          // rotation
      const size_t base = (((size_t)bh * 16 + chk) * 64 + (col & 63)) * 64 + keyp;
      union { __bf16 hh[4]; uint2 uu; } pk;
      #pragma unroll
      for (int r = 0; r < 4; r++) pk.hh[r] = (__bf16)(av[mi][ni][r] + bvv);
      *(uint2*)(vp + base) = pk.uu;
    }
  }
}

// ---------------------------------------------------- O-proj: 128x64 tiles, 512 blocks (R8)
__global__ __launch_bounds__(256) void gemm_o(
    const __bf16* __restrict__ A, const __bf16* __restrict__ W,
    const float* __restrict__ bias, float* __restrict__ out) {
  // bijective XCD swizzle: id 0..511; xcd=id&7, j=id>>3; by=(j&3)*8+xcd, bx=j>>2
  const int id = blockIdx.x + (blockIdx.y << 4);
  const int xcd = id & 7;
  const int j = id >> 3;
  const int by = (j & 3) * 8 + xcd;
  const int bx = j >> 2;                 // 0..15

  __shared__ __bf16 As[2 * 8192];        // 2 x 128 rows x 64 k  (32 KB)
  __shared__ __bf16 Bs[2 * 4096];        // 2 x  64 rows x 64 k  (16 KB)

  const int tid = threadIdx.x;
  const int w = tid >> 6, l = tid & 63;
  const int quad = l >> 4, l16 = l & 15;
  const int wy = w >> 1, wx = w & 1;
  const int row0 = by * 128;
  const int col0 = bx * 64;

  const f32x4 fzero = {0.f, 0.f, 0.f, 0.f};
  f32x4 acc[4][2];
  for (int i = 0; i < 4; i++)
    for (int jj = 0; jj < 2; jj++) acc[i][jj] = fzero;

  const int rk = tid >> 3;                       // 0..31
  const int csw = (((tid & 7) ^ (rk & 7)) * 8);
  const int tid8 = tid * 8;
  const __bf16* aS = A + (size_t)(row0 + rk) * D_MODEL + csw;
  const __bf16* bS = W + (size_t)(col0 + rk) * D_MODEL + csw;

  const int pch0 = ((0 * 4 + quad) ^ (l16 & 7)) * 8;
  const int pch1 = ((1 * 4 + quad) ^ (l16 & 7)) * 8;

  // prologue: stage K-tile 0 (A: 4 calls, B: 2 calls)
  #pragma unroll
  for (int p = 0; p < 4; ++p)
    async16(&As[p * 2048 + tid8], aS + (size_t)p * 32 * D_MODEL);
  #pragma unroll
  for (int p = 0; p < 2; ++p)
    async16(&Bs[p * 2048 + tid8], bS + (size_t)p * 32 * D_MODEL);

  #pragma unroll 2
  for (int t = 0; t < 16; ++t) {
    const int rbA = (t & 1) << 13;
    const int rbB = (t & 1) << 12;
    if (t < 15) {
      const int sbA = ((t + 1) & 1) << 13;
      const int sbB = ((t + 1) & 1) << 12;
      const size_t kk = (size_t)(t + 1) * 64;
      #pragma unroll
      for (int p = 0; p < 4; ++p)
        async16(&As[sbA + p * 2048 + tid8], aS + (size_t)p * 32 * D_MODEL + kk);
      #pragma unroll
      for (int p = 0; p < 2; ++p)
        async16(&Bs[sbB + p * 2048 + tid8], bS + (size_t)p * 32 * D_MODEL + kk);
      asm volatile("s_waitcnt vmcnt(6)" ::: "memory");   // tile t landed; t+1 in flight
    } else {
      asm volatile("s_waitcnt vmcnt(0)" ::: "memory");
    }
    __builtin_amdgcn_s_barrier();
    #pragma unroll
    for (int ks = 0; ks < 2; ++ks) {
      const int pch = ks ? pch1 : pch0;
      bf16x8 af[4], bfr[2];
      #pragma unroll
      for (int mi = 0; mi < 4; mi++) af[mi]  = *(const bf16x8*)&As[rbA + (wy * 64 + mi * 16 + l16) * 64 + pch];
      #pragma unroll
      for (int ni = 0; ni < 2; ni++) bfr[ni] = *(const bf16x8*)&Bs[rbB + (wx * 32 + ni * 16 + l16) * 64 + pch];
      #pragma unroll
      for (int mi = 0; mi < 4; mi++)
        #pragma unroll
        for (int ni = 0; ni < 2; ni++)
          acc[mi][ni] = mfma16(af[mi], bfr[ni], acc[mi][ni]);
    }
    __builtin_amdgcn_s_barrier();
  }

  #pragma unroll
  for (int ni = 0; ni < 2; ni++) {
    const int col = col0 + wx * 32 + ni * 16 + l16;
    const float bv = bias[col];
    #pragma unroll
    for (int mi = 0; mi < 4; mi++) {
      const int row = row0 + wy * 64 + mi * 16 + quad * 4;
      #pragma unroll
      for (int r = 0; r < 4; r++)
        out[(size_t)(row + r) * D_MODEL + col] = acc[mi][ni][r] + bv;
    }
  }
}

// ------------------------------------------------------- attention, MERGED SWEEP
// R7 structure + gg-balance remap: pass count per block = 16-gg (16..9). Co-resident
// pairs (id, id+256) had gg pairs (g, g+4) -> 28 vs 22 total passes (+-12% critical-
// path imbalance). Remap gg ^= (gg&4)?3:0 -> pairs (0,7),(1,6),(2,5),(3,4), all 25.
__global__ __launch_bounds__(256, 2) void attn_kernel(
    const __bf16* __restrict__ Qb, const __bf16* __restrict__ Kp,
    const __bf16* __restrict__ Vp, const float* __restrict__ vimp,
    __bf16* __restrict__ Ob) {
  const int id = blockIdx.x;
  const int bh = id & 63;
  const int ggi = id >> 6;                // 0..7
  const int gg = ggi ^ ((ggi & 4) ? 3 : 0);   // balance co-resident pass counts
  const int b = bh >> 4, h = bh & 15;
  const int tid = threadIdx.x;
  const int wave = tid >> 6, lane = tid & 63;
  const int quad = lane >> 4, l16 = lane & 15;

  __shared__ __bf16 Kl[3][4096];          // 64 keys x 64 dims (rotated rows)
  __shared__ __bf16 Vl[3][4096];          // 64 dims x 64 keys (rotated rows)
  __shared__ __bf16 Ps[4][16][72];

  const __bf16* kbase = Kp + (size_t)bh * (SEQ * HD);
  const __bf16* vbase = Vp + (size_t)bh * (SEQ * HD);
  const float* vimpH = vimp + h * SEQ;

  const int rot0 = ((quad + (l16 & 7)) & 7) * 8;        // logical cols quad*8..+7
  const int rot1 = ((quad + 4 + (l16 & 7)) & 7) * 8;    // logical cols 32+quad*8..+7
  const int frow = l16 * 64;

  const int g0 = gg, g1 = 15 - gg;        // g0 < g1 always (7 < 8)

  const int qrow0 = g0 * 64 + wave * 16 + l16;
  const int qrow1 = g1 * 64 + wave * 16 + l16;
  const __bf16* qp0 = Qb + (size_t)(b * SEQ + qrow0) * D_MODEL + h * HD;
  const __bf16* qp1 = Qb + (size_t)(b * SEQ + qrow1) * D_MODEL + h * HD;
  bf16x8 qA0 = *(const bf16x8*)(qp0 + quad * 8);        // Q pre-scaled by QSC in gemm
  bf16x8 qA1 = *(const bf16x8*)(qp0 + 32 + quad * 8);
  bf16x8 qB0 = *(const bf16x8*)(qp1 + quad * 8);
  bf16x8 qB1 = *(const bf16x8*)(qp1 + 32 + quad * 8);

  // prologue: DMA chunks 0 and 1
  async16(&Kl[0][tid * 8], kbase + tid * 8);
  async16(&Kl[0][2048 + tid * 8], kbase + 2048 + tid * 8);
  async16(&Vl[0][tid * 8], vbase + tid * 8);
  async16(&Vl[0][2048 + tid * 8], vbase + 2048 + tid * 8);
  async16(&Kl[1][tid * 8], kbase + 4096 + tid * 8);
  async16(&Kl[1][2048 + tid * 8], kbase + 4096 + 2048 + tid * 8);
  async16(&Vl[1][tid * 8], vbase + 4096 + tid * 8);
  async16(&Vl[1][2048 + tid * 8], vbase + 4096 + 2048 + tid * 8);

  float l0 = 0.f, l1 = 0.f;
  f32x4 o0[4], o1[4];
  #pragma unroll
  for (int td = 0; td < 4; td++) {
    o0[td][0] = 0.f; o0[td][1] = 0.f; o0[td][2] = 0.f; o0[td][3] = 0.f;
    o1[td][0] = 0.f; o1[td][1] = 0.f; o1[td][2] = 0.f; o1[td][3] = 0.f;
  }

  #pragma unroll 1
  for (int c = 0; c <= g1; ++c) {
    const int buf = c % 3;
    if (c < g1) asm volatile("s_waitcnt vmcnt(4)" ::: "memory");
    else        asm volatile("s_waitcnt vmcnt(0)" ::: "memory");
    __builtin_amdgcn_s_barrier();
    const int kc = c * 64;
    // vi(c) first (its compiler wait will count DMA(c+2) behind it -> vmcnt(4))
    float4 vi[4];
    #pragma unroll
    for (int t = 0; t < 4; t++) vi[t] = *(const float4*)(vimpH + kc + t * 16 + quad * 4);
    __builtin_amdgcn_sched_barrier(0);
    if (c + 2 <= g1) {                    // DMA chunk c+2 into buf (c+2)%3
      const int nb = (c + 2) % 3;
      const __bf16* gk = kbase + (size_t)(c + 2) * 4096;
      const __bf16* gv = vbase + (size_t)(c + 2) * 4096;
      async16(&Kl[nb][tid * 8], gk + tid * 8);
      async16(&Kl[nb][2048 + tid * 8], gk + 2048 + tid * 8);
      async16(&Vl[nb][tid * 8], gv + tid * 8);
      async16(&Vl[nb][2048 + tid * 8], gv + 2048 + tid * 8);
    }
    __builtin_amdgcn_sched_barrier(0);

    bf16x8 kf0[4], kf1[4], vfr0[4], vfr1[4];
    #pragma unroll
    for (int t = 0; t < 4; t++) {
      kf0[t] = *(const bf16x8*)&Kl[buf][t * 1024 + frow + rot0];
      kf1[t] = *(const bf16x8*)&Kl[buf][t * 1024 + frow + rot1];
    }
    #pragma unroll
    for (int td = 0; td < 4; td++) {
      vfr0[td] = *(const bf16x8*)&Vl[buf][td * 1024 + frow + rot0];
      vfr1[td] = *(const bf16x8*)&Vl[buf][td * 1024 + frow + rot1];
    }
    const f32x4 fz = {0.f, 0.f, 0.f, 0.f};

    // ---------------- tile1 (rows qrow1): active every pass
    {
      f32x4 sacc[4];
      __builtin_amdgcn_s_setprio(1);
      #pragma unroll
      for (int t = 0; t < 4; t++) {
        sacc[t] = mfma16(kf0[t], qB0, fz);
        sacc[t] = mfma16(kf1[t], qB1, sacc[t]);
      }
      __builtin_amdgcn_s_setprio(0);
      float p[4][4];
      float lsum = 0.f;
      #pragma unroll
      for (int t = 0; t < 4; t++) {
        const float vib[4] = {vi[t].x, vi[t].y, vi[t].z, vi[t].w};
        if (c == g1) {
          #pragma unroll
          for (int r = 0; r < 4; r++) {
            float pp = fexp2(sacc[t][r] + BSC * vib[r]);
            pp = (kc + t * 16 + quad * 4 + r <= qrow1) ? pp : 0.f;
            p[t][r] = pp;
            lsum += pp;
          }
        } else {
          #pragma unroll
          for (int r = 0; r < 4; r++) {
            float pp = fexp2(sacc[t][r] + BSC * vib[r]);
            p[t][r] = pp;
            lsum += pp;
          }
        }
      }
      l1 += lsum;
      #pragma unroll
      for (int t = 0; t < 4; t++) {
        union { __bf16 hh[4]; uint2 uu; } pk;
        #pragma unroll
        for (int r = 0; r < 4; r++) pk.hh[r] = (__bf16)p[t][r];
        *(uint2*)&Ps[wave][l16][t * 16 + quad * 4] = pk.uu;
      }
      bf16x8 pf0 = *(const bf16x8*)&Ps[wave][l16][quad * 8];
      bf16x8 pf1 = *(const bf16x8*)&Ps[wave][l16][32 + quad * 8];
      __builtin_amdgcn_s_setprio(1);
      #pragma unroll
      for (int td = 0; td < 4; td++) {
        o1[td] = mfma16(vfr0[td], pf0, o1[td]);
        o1[td] = mfma16(vfr1[td], pf1, o1[td]);
      }
      __builtin_amdgcn_s_setprio(0);
    }

    // ---------------- tile0 (rows qrow0): active while c <= g0 (block-uniform)
    if (c <= g0) {
      f32x4 sacc[4];
      __builtin_amdgcn_s_setprio(1);
      #pragma unroll
      for (int t = 0; t < 4; t++) {
        sacc[t] = mfma16(kf0[t], qA0, fz);
        sacc[t] = mfma16(kf1[t], qA1, sacc[t]);
      }
      __builtin_amdgcn_s_setprio(0);
      float p[4][4];
      float lsum = 0.f;
      #pragma unroll
      for (int t = 0; t < 4; t++) {
        const float vib[4] = {vi[t].x, vi[t].y, vi[t].z, vi[t].w};
        if (c == g0) {
          #pragma unroll
          for (int r = 0; r < 4; r++) {
            float pp = fexp2(sacc[t][r] + BSC * vib[r]);
            pp = (kc + t * 16 + quad * 4 + r <= qrow0) ? pp : 0.f;
            p[t][r] = pp;
            lsum += pp;
          }
        } else {
          #pragma unroll
          for (int r = 0; r < 4; r++) {
            float pp = fexp2(sacc[t][r] + BSC * vib[r]);
            p[t][r] = pp;
            lsum += pp;
          }
        }
      }
      l0 += lsum;
      #pragma unroll
      for (int t = 0; t < 4; t++) {
        union { __bf16 hh[4]; uint2 uu; } pk;
        #pragma unroll
        for (int r = 0; r < 4; r++) pk.hh[r] = (__bf16)p[t][r];
        *(uint2*)&Ps[wave][l16][t * 16 + quad * 4] = pk.uu;
      }
      bf16x8 pf0 = *(const bf16x8*)&Ps[wave][l16][quad * 8];
      bf16x8 pf1 = *(const bf16x8*)&Ps[wave][l16][32 + quad * 8];
      __builtin_amdgcn_s_setprio(1);
      #pragma unroll
      for (int td = 0; td < 4; td++) {
        o0[td] = mfma16(vfr0[td], pf0, o0[td]);
        o0[td] = mfma16(vfr1[td], pf1, o0[td]);
      }
      __builtin_amdgcn_s_setprio(0);
      if (c == g0) {                      // tile0 complete: write out
        float L = l0;
        L += __shfl_xor(L, 16);
        L += __shfl_xor(L, 32);
        const float il = 1.0f / L;
        __bf16* op = Ob + (size_t)(b * SEQ + qrow0) * D_MODEL + h * HD;
        #pragma unroll
        for (int td = 0; td < 4; td++) {
          union { __bf16 hh[4]; uint2 uu; } pk;
          #pragma unroll
          for (int r = 0; r < 4; r++) pk.hh[r] = (__bf16)(o0[td][r] * il);
          *(uint2*)(op + td * 16 + quad * 4) = pk.uu;
        }
      }
    }
  }

  // tile1 epilogue
  float L = l1;
  L += __shfl_xor(L, 16);
  L += __shfl_xor(L, 32);
  const float il = 1.0f / L;
  __bf16* op = Ob + (size_t)(b * SEQ + qrow1) * D_MODEL + h * HD;
  #pragma unroll
  for (int td = 0; td < 4; td++) {
    union { __bf16 hh[4]; uint2 uu; } pk;
    #pragma unroll
    for (int r = 0; r < 4; r++) pk.hh[r] = (__bf16)(o1[td][r] * il);
    *(uint2*)(op + td * 16 + quad * 4) = pk.uu;
  }
}

// ---------------------------------------------------------------------------
extern "C" void kernel_launch(void* const* d_in, const int* in_sizes, int n_in,
                              void* d_out, int out_size, void* d_ws, size_t ws_size,
                              hipStream_t stream) {
  const float* x     = (const float*)d_in[0];
  const float* Wq    = (const float*)d_in[1];
  const float* bq    = (const float*)d_in[2];
  const float* Wk    = (const float*)d_in[3];
  const float* bk    = (const float*)d_in[4];
  const float* Wv    = (const float*)d_in[5];
  const float* bv    = (const float*)d_in[6];
  const float* Wo    = (const float*)d_in[7];
  const float* bo    = (const float*)d_in[8];
  const float* Wimp  = (const float*)d_in[9];
  const float* bimp  = (const float*)d_in[10];
  // d_in[11] = k_ema (unused: kimp bias is per-q-row constant, cancels in softmax)
  const float* v_ema = (const float*)d_in[12];
  float* out = (float*)d_out;

  char* ws = (char*)d_ws;
  __bf16* x_bf  = (__bf16*)(ws);                        // 8 MB
  __bf16* wq_bf = (__bf16*)(ws + (8ull  << 20));        // 2 MB each
  __bf16* wk_bf = (__bf16*)(ws + (10ull << 20));
  __bf16* wv_bf = (__bf16*)(ws + (12ull << 20));
  __bf16* wo_bf = (__bf16*)(ws + (14ull << 20));
  __bf16* q_bf  = (__bf16*)(ws + (16ull << 20));        // 8 MB each
  __bf16* kp_bf = (__bf16*)(ws + (24ull << 20));        // K packed+rotated [bh][key][64]
  __bf16* vp_bf = (__bf16*)(ws + (32ull << 20));        // V packed+rotated [bh][ch][d][64]
  __bf16* a_bf  = (__bf16*)(ws + (40ull << 20));
  float*  vimp  = (float*)(ws + (48ull << 20));         // 64 KB

  prep_kernel<<<8448, 256, 0, stream>>>(
      x, Wq, Wk, Wv, Wo, v_ema, Wimp, bimp,
      x_bf, wq_bf, wk_bf, wv_bf, wo_bf, vimp);

  // MERGED Q,K,V projections: one A-tile stage feeds all three products (R9 exact).
  gemm_qkv<<<dim3(16, 32), 256, 0, stream>>>(
      x_bf, wq_bf, wk_bf, wv_bf, bq, bk, bv, q_bf, kp_bf, vp_bf);

  attn_kernel<<<dim3(512), 256, 0, stream>>>(
      q_bf, kp_bf, vp_bf, vimp, a_bf);

  // O-projection: 128x64 tiles, 512 blocks -> 2 blocks/CU co-resident
  gemm_o<<<dim3(16, 32), 256, 0, stream>>>(a_bf, wo_bf, bo, out);
}